// Round 1
// baseline (23.666 us; speedup 1.0000x reference)
//
#include <hip/hip_runtime.h>

#define K 512            // NUM_CATEGORIES
#define MAIN_BLOCK 256

// ---------------- kernel 1: bitonic sort of 512 codes (1 block, 256 threads) -------------
__global__ __launch_bounds__(256) void vq_sort_codes(const float* __restrict__ codes,
                                                     float* __restrict__ sorted) {
    __shared__ float s[K];
    const int t = threadIdx.x;            // 256 threads, 2 elements each
    s[t]       = codes[t];
    s[t + 256] = codes[t + 256];
    for (int k = 2; k <= K; k <<= 1) {
        for (int j = k >> 1; j > 0; j >>= 1) {
            __syncthreads();
            for (int idx = t; idx < K; idx += 256) {
                const int ixj = idx ^ j;
                if (ixj > idx) {
                    const float a = s[idx], b = s[ixj];
                    const bool up = ((idx & k) == 0);
                    if ((a > b) == up) { s[idx] = b; s[ixj] = a; }
                }
            }
        }
    }
    __syncthreads();
    sorted[t]       = s[t];
    sorted[t + 256] = s[t + 256];
}

// ---------------- kernel 2: quantize + partial loss reduction ---------------------------
__global__ __launch_bounds__(MAIN_BLOCK) void vq_main(const float* __restrict__ enc,
                                                      const float* __restrict__ sorted,
                                                      float* __restrict__ out,
                                                      float* __restrict__ partial,
                                                      int n4) {
    __shared__ float c[K];
    c[threadIdx.x]       = sorted[threadIdx.x];
    c[threadIdx.x + 256] = sorted[threadIdx.x + 256];
    __syncthreads();

    const int tid = blockIdx.x * blockDim.x + threadIdx.x;
    float lsum = 0.0f;

    if (tid < n4) {
        const float4 x = reinterpret_cast<const float4*>(enc)[tid];
        float xs[4] = {x.x, x.y, x.z, x.w};
        float ys[4];
#pragma unroll
        for (int e = 0; e < 4; ++e) {
            const float xe = xs[e];
            // branchless binary search: lo = min(count of codes < xe, K-1)
            int lo = 0;
#pragma unroll
            for (int step = 256; step >= 1; step >>= 1) {
                if (c[lo + step - 1] < xe) lo += step;
            }
            const float ch = c[lo];
            const float cl = c[lo > 0 ? lo - 1 : 0];
            // interior: cl < xe <= ch (true distances); edges degenerate to same code
            const float q = ((xe - cl) <= (ch - xe)) ? cl : ch;
            ys[e] = q;
            const float d = q - xe;
            lsum += d * d;
        }
        float4 y;
        y.x = ys[0]; y.y = ys[1]; y.z = ys[2]; y.w = ys[3];
        reinterpret_cast<float4*>(out)[tid] = y;
    }

    // block reduction of lsum (wave shuffle + LDS across 4 waves)
#pragma unroll
    for (int off = 32; off > 0; off >>= 1)
        lsum += __shfl_down(lsum, off, 64);
    __shared__ float red[MAIN_BLOCK / 64];
    const int wave = threadIdx.x >> 6;
    const int lane = threadIdx.x & 63;
    if (lane == 0) red[wave] = lsum;
    __syncthreads();
    if (threadIdx.x == 0) {
        float s = 0.0f;
#pragma unroll
        for (int w = 0; w < MAIN_BLOCK / 64; ++w) s += red[w];
        partial[blockIdx.x] = s;
    }
}

// ---------------- kernel 3: finalize loss (1 block) --------------------------------------
__global__ __launch_bounds__(256) void vq_finalize(const float* __restrict__ partial,
                                                   float* __restrict__ loss_out,
                                                   int nblocks, float scale) {
    float s = 0.0f;
    for (int i = threadIdx.x; i < nblocks; i += 256) s += partial[i];
#pragma unroll
    for (int off = 32; off > 0; off >>= 1)
        s += __shfl_down(s, off, 64);
    __shared__ float red[4];
    if ((threadIdx.x & 63) == 0) red[threadIdx.x >> 6] = s;
    __syncthreads();
    if (threadIdx.x == 0) loss_out[0] = (red[0] + red[1] + red[2] + red[3]) * scale;
}

extern "C" void kernel_launch(void* const* d_in, const int* in_sizes, int n_in,
                              void* d_out, int out_size, void* d_ws, size_t ws_size,
                              hipStream_t stream) {
    const float* enc   = (const float*)d_in[0];   // [1024*256] f32
    const float* codes = (const float*)d_in[1];   // [512] f32
    float* out = (float*)d_out;                   // [N] latent + [1] loss

    const int N  = in_sizes[0];                   // 262144
    const int n4 = N / 4;                         // 65536 (N divisible by 4)
    const int nblocks = (n4 + MAIN_BLOCK - 1) / MAIN_BLOCK;  // 256

    float* ws_sorted  = (float*)d_ws;             // 512 floats
    float* ws_partial = ws_sorted + K;            // nblocks floats

    const int rows = N / 256;                     // batch dim = 1024
    const float scale = 2.0f / (float)rows;       // (1 + BETA) / B

    vq_sort_codes<<<1, 256, 0, stream>>>(codes, ws_sorted);
    vq_main<<<nblocks, MAIN_BLOCK, 0, stream>>>(enc, ws_sorted, out, ws_partial, n4);
    vq_finalize<<<1, 256, 0, stream>>>(ws_partial, out + N, nblocks, scale);
}